// Round 1
// baseline (476.553 us; speedup 1.0000x reference)
//
#include <hip/hip_runtime.h>
#include <hip/hip_bf16.h>

#define NN 100000
#define NE 1600000
#define FIN 512
#define FH 32
#define FC 16

// ---------------- degree / norm ----------------

__global__ void k_init_deg(float* __restrict__ deg) {
    int n = blockIdx.x * blockDim.x + threadIdx.x;
    if (n < NN) deg[n] = 1.0f;  // self-loop contributes 1
}

__global__ void k_count(const int* __restrict__ col, float* __restrict__ deg) {
    int e = blockIdx.x * blockDim.x + threadIdx.x;
    if (e < NE) atomicAdd(&deg[col[e]], 1.0f);
}

__global__ void k_dis(float* __restrict__ deg) {
    int n = blockIdx.x * blockDim.x + threadIdx.x;
    if (n < NN) deg[n] = rsqrtf(deg[n]);  // deg >= 1 always (self-loop)
}

__global__ void k_norm(const int* __restrict__ row, const int* __restrict__ col,
                       const float* __restrict__ dis, float* __restrict__ norm) {
    int e = blockIdx.x * blockDim.x + threadIdx.x;
    if (e < NE) norm[e] = dis[row[e]] * dis[col[e]];
}

// ---------------- GEMM1: h1 = x @ W1  (512 -> 32) ----------------
// one thread per node, W1 staged in LDS (64 KB), 32 f32 accumulators.

__global__ __launch_bounds__(256) void k_gemm1(const float* __restrict__ x,
                                               const float* __restrict__ W1,
                                               float* __restrict__ h1) {
    __shared__ float Wl[FIN * FH];  // 64 KB
    for (int i = threadIdx.x; i < FIN * FH / 4; i += 256)
        ((float4*)Wl)[i] = ((const float4*)W1)[i];
    __syncthreads();

    int n = blockIdx.x * blockDim.x + threadIdx.x;
    if (n >= NN) return;

    float acc[FH];
#pragma unroll
    for (int j = 0; j < FH; ++j) acc[j] = 0.0f;

    const float4* xr = (const float4*)(x + (size_t)n * FIN);
    for (int k4 = 0; k4 < FIN / 4; ++k4) {
        float4 xv = xr[k4];
        const float* xs = (const float*)&xv;
#pragma unroll
        for (int kk = 0; kk < 4; ++kk) {
            float xk = xs[kk];
            const float* wrow = &Wl[(k4 * 4 + kk) * FH];
#pragma unroll
            for (int j = 0; j < FH; ++j) acc[j] += xk * wrow[j];
        }
    }
    float4* out = (float4*)(h1 + (size_t)n * FH);
#pragma unroll
    for (int j = 0; j < FH / 4; ++j)
        out[j] = make_float4(acc[4 * j], acc[4 * j + 1], acc[4 * j + 2], acc[4 * j + 3]);
}

// ---------------- edge scatter: acc[col] += h[row] * norm ----------------
// one thread per (edge, feature)

template <int F>
__global__ void k_scatter(const int* __restrict__ row, const int* __restrict__ col,
                          const float* __restrict__ norm, const float* __restrict__ h,
                          float* __restrict__ acc) {
    unsigned int gid = blockIdx.x * blockDim.x + threadIdx.x;
    if (gid >= (unsigned int)NE * F) return;
    unsigned int e = gid / F;
    unsigned int f = gid % F;
    int r = row[e], c = col[e];
    float v = h[(size_t)r * F + f] * norm[e];
    atomicAdd(&acc[(size_t)c * F + f], v);
}

// ---------------- finalize layer1 (+ self-loop + bias + relu) fused with GEMM2 ----------------

__global__ void k_fin1_gemm2(const float* __restrict__ acc1, const float* __restrict__ h1,
                             const float* __restrict__ dis, const float* __restrict__ b1,
                             const float* __restrict__ W2, float* __restrict__ h2) {
    int n = blockIdx.x * blockDim.x + threadIdx.x;
    if (n >= NN) return;
    float d2 = dis[n] * dis[n];
    float hr[FH];
#pragma unroll
    for (int j = 0; j < FH; ++j) {
        float v = acc1[(size_t)n * FH + j] + h1[(size_t)n * FH + j] * d2 + b1[j];
        hr[j] = v > 0.0f ? v : 0.0f;
    }
#pragma unroll
    for (int j = 0; j < FC; ++j) {
        float s = 0.0f;
#pragma unroll
        for (int k = 0; k < FH; ++k) s += hr[k] * W2[k * FC + j];
        h2[(size_t)n * FC + j] = s;
    }
}

// ---------------- finalize layer2 + log_softmax ----------------

__global__ void k_fin2(float* __restrict__ out, const float* __restrict__ h2,
                       const float* __restrict__ dis, const float* __restrict__ b2) {
    int n = blockIdx.x * blockDim.x + threadIdx.x;
    if (n >= NN) return;
    float d2 = dis[n] * dis[n];
    float v[FC];
    float m = -1e30f;
#pragma unroll
    for (int j = 0; j < FC; ++j) {
        float t = out[(size_t)n * FC + j] + h2[(size_t)n * FC + j] * d2 + b2[j];
        v[j] = t;
        m = fmaxf(m, t);
    }
    float s = 0.0f;
#pragma unroll
    for (int j = 0; j < FC; ++j) s += __expf(v[j] - m);
    float ls = logf(s);
#pragma unroll
    for (int j = 0; j < FC; ++j) out[(size_t)n * FC + j] = v[j] - m - ls;
}

extern "C" void kernel_launch(void* const* d_in, const int* in_sizes, int n_in,
                              void* d_out, int out_size, void* d_ws, size_t ws_size,
                              hipStream_t stream) {
    const float* x  = (const float*)d_in[0];
    const int*   ei = (const int*)d_in[1];
    const float* W1 = (const float*)d_in[2];
    const float* b1 = (const float*)d_in[3];
    const float* W2 = (const float*)d_in[4];
    const float* b2 = (const float*)d_in[5];
    float* out = (float*)d_out;

    const int* row = ei;
    const int* col = ei + NE;

    // workspace layout (floats)
    float* ws   = (float*)d_ws;
    float* deg  = ws;                    // NN        (becomes dis in place)
    float* norm = deg + NN;              // NE
    float* h1   = norm + NE;             // NN*FH
    float* acc1 = h1 + (size_t)NN * FH;  // NN*FH
    float* h2   = acc1 + (size_t)NN * FH;// NN*FC

    // zero accumulators
    hipMemsetAsync(acc1, 0, (size_t)NN * FH * sizeof(float), stream);
    hipMemsetAsync(d_out, 0, (size_t)NN * FC * sizeof(float), stream);

    const int B = 256;
    int gbN = (NN + B - 1) / B;
    int gbE = (NE + B - 1) / B;

    k_init_deg<<<gbN, B, 0, stream>>>(deg);
    k_count<<<gbE, B, 0, stream>>>(col, deg);
    k_dis<<<gbN, B, 0, stream>>>(deg);
    k_norm<<<gbE, B, 0, stream>>>(row, col, deg, norm);

    k_gemm1<<<gbN, B, 0, stream>>>(x, W1, h1);

    unsigned int tot1 = (unsigned int)NE * FH;
    k_scatter<FH><<<(tot1 + B - 1) / B, B, 0, stream>>>(row, col, norm, h1, acc1);

    k_fin1_gemm2<<<gbN, B, 0, stream>>>(acc1, h1, deg, b1, W2, h2);

    unsigned int tot2 = (unsigned int)NE * FC;
    k_scatter<FC><<<(tot2 + B - 1) / B, B, 0, stream>>>(row, col, norm, h2, out);

    k_fin2<<<gbN, B, 0, stream>>>(out, h2, deg, b2);
}

// Round 2
// 416.150 us; speedup vs baseline: 1.1451x; 1.1451x over previous
//
#include <hip/hip_runtime.h>
#include <hip/hip_bf16.h>

#define NN 100000
#define NE 1600000
#define FIN 512
#define FH 32
#define FC 16
#define SCAN_B 1024
#define NBLK ((NN + SCAN_B - 1) / SCAN_B)  // 98

// ---------------- degree histogram ----------------

__global__ void k_count(const int* __restrict__ col, int* __restrict__ cnt) {
    int e = blockIdx.x * blockDim.x + threadIdx.x;
    if (e < NE) atomicAdd(&cnt[col[e]], 1);
}

__global__ void k_dis(const int* __restrict__ cnt, float* __restrict__ dis) {
    int n = blockIdx.x * blockDim.x + threadIdx.x;
    if (n < NN) dis[n] = rsqrtf((float)cnt[n] + 1.0f);  // +1 self-loop
}

// ---------------- exclusive prefix scan of cnt -> off (3 kernels) ----------------

__global__ __launch_bounds__(SCAN_B) void k_blocksum(const int* __restrict__ cnt,
                                                     int* __restrict__ part) {
    __shared__ int s[SCAN_B];
    int i = blockIdx.x * SCAN_B + threadIdx.x;
    s[threadIdx.x] = (i < NN) ? cnt[i] : 0;
    __syncthreads();
    for (int st = SCAN_B / 2; st > 0; st >>= 1) {
        if (threadIdx.x < st) s[threadIdx.x] += s[threadIdx.x + st];
        __syncthreads();
    }
    if (threadIdx.x == 0) part[blockIdx.x] = s[0];
}

__global__ void k_scanpart(int* __restrict__ part) {
    if (threadIdx.x == 0 && blockIdx.x == 0) {
        int run = 0;
        for (int b = 0; b < NBLK; ++b) {
            int v = part[b];
            part[b] = run;
            run += v;
        }
    }
}

__global__ __launch_bounds__(SCAN_B) void k_scanblock(const int* __restrict__ cnt,
                                                      const int* __restrict__ part,
                                                      int* __restrict__ off) {
    __shared__ int s[SCAN_B];
    int i = blockIdx.x * SCAN_B + threadIdx.x;
    int v = (i < NN) ? cnt[i] : 0;
    s[threadIdx.x] = v;
    __syncthreads();
    for (int st = 1; st < SCAN_B; st <<= 1) {
        int add = (threadIdx.x >= st) ? s[threadIdx.x - st] : 0;
        __syncthreads();
        s[threadIdx.x] += add;
        __syncthreads();
    }
    if (i < NN) off[i] = part[blockIdx.x] + s[threadIdx.x] - v;  // exclusive
    if (i == NN - 1) off[NN] = part[blockIdx.x] + s[threadIdx.x];
}

// ---------------- CSR fill: src[pos]=row, wgt[pos]=dis[row]*dis[col] ----------------

__global__ void k_fill(const int* __restrict__ row, const int* __restrict__ col,
                       const float* __restrict__ dis, const int* __restrict__ off,
                       int* __restrict__ cur, int* __restrict__ src,
                       float* __restrict__ wgt) {
    int e = blockIdx.x * blockDim.x + threadIdx.x;
    if (e >= NE) return;
    int r = row[e], c = col[e];
    int p = off[c] + atomicAdd(&cur[c], 1);
    src[p] = r;
    wgt[p] = dis[r] * dis[c];
}

// ---------------- GEMM1: h1 = x @ W1  (512 -> 32) ----------------

__global__ __launch_bounds__(256) void k_gemm1(const float* __restrict__ x,
                                               const float* __restrict__ W1,
                                               float* __restrict__ h1) {
    __shared__ float Wl[FIN * FH];  // 64 KB
    for (int i = threadIdx.x; i < FIN * FH / 4; i += 256)
        ((float4*)Wl)[i] = ((const float4*)W1)[i];
    __syncthreads();

    int n = blockIdx.x * blockDim.x + threadIdx.x;
    if (n >= NN) return;

    float acc[FH];
#pragma unroll
    for (int j = 0; j < FH; ++j) acc[j] = 0.0f;

    const float4* xr = (const float4*)(x + (size_t)n * FIN);
    for (int k4 = 0; k4 < FIN / 4; ++k4) {
        float4 xv = xr[k4];
        const float* xs = (const float*)&xv;
#pragma unroll
        for (int kk = 0; kk < 4; ++kk) {
            float xk = xs[kk];
            const float* wrow = &Wl[(k4 * 4 + kk) * FH];
#pragma unroll
            for (int j = 0; j < FH; ++j) acc[j] += xk * wrow[j];
        }
    }
    float4* outp = (float4*)(h1 + (size_t)n * FH);
#pragma unroll
    for (int j = 0; j < FH / 4; ++j)
        outp[j] = make_float4(acc[4 * j], acc[4 * j + 1], acc[4 * j + 2], acc[4 * j + 3]);
}

// ---------------- gather layer1 + self-loop + bias + relu -> hr ----------------
// 32 lanes per node, lane = feature

__global__ __launch_bounds__(256) void k_gather1(const int* __restrict__ off,
                                                 const int* __restrict__ src,
                                                 const float* __restrict__ wgt,
                                                 const float* __restrict__ h1,
                                                 const float* __restrict__ dis,
                                                 const float* __restrict__ b1,
                                                 float* __restrict__ hr) {
    int g = blockIdx.x * (256 / FH) + threadIdx.x / FH;
    int f = threadIdx.x & (FH - 1);
    if (g >= NN) return;
    int s0 = off[g], s1 = off[g + 1];
    float acc = 0.0f;
    for (int i = s0; i < s1; ++i) {
        int r = src[i];
        acc += h1[(size_t)r * FH + f] * wgt[i];
    }
    float d2 = dis[g] * dis[g];
    float v = acc + h1[(size_t)g * FH + f] * d2 + b1[f];
    hr[(size_t)g * FH + f] = v > 0.0f ? v : 0.0f;
}

// ---------------- GEMM2: h2 = hr @ W2 (32 -> 16) ----------------

__global__ __launch_bounds__(256) void k_gemm2(const float* __restrict__ hr,
                                               const float* __restrict__ W2,
                                               float* __restrict__ h2) {
    __shared__ float Wl[FH * FC];  // 2 KB
    for (int i = threadIdx.x; i < FH * FC; i += 256) Wl[i] = W2[i];
    __syncthreads();
    int n = blockIdx.x * blockDim.x + threadIdx.x;
    if (n >= NN) return;
    float h[FH];
    const float4* hp = (const float4*)(hr + (size_t)n * FH);
#pragma unroll
    for (int j = 0; j < FH / 4; ++j) {
        float4 t = hp[j];
        h[4 * j] = t.x; h[4 * j + 1] = t.y; h[4 * j + 2] = t.z; h[4 * j + 3] = t.w;
    }
#pragma unroll
    for (int j = 0; j < FC; ++j) {
        float s = 0.0f;
#pragma unroll
        for (int k = 0; k < FH; ++k) s += h[k] * Wl[k * FC + j];
        h2[(size_t)n * FC + j] = s;
    }
}

// ---------------- gather layer2 + self-loop + bias + log_softmax -> out ----------------
// 16 lanes per node, lane = class

__global__ __launch_bounds__(256) void k_gather2(const int* __restrict__ off,
                                                 const int* __restrict__ src,
                                                 const float* __restrict__ wgt,
                                                 const float* __restrict__ h2,
                                                 const float* __restrict__ dis,
                                                 const float* __restrict__ b2,
                                                 float* __restrict__ out) {
    int g = blockIdx.x * (256 / FC) + threadIdx.x / FC;
    int f = threadIdx.x & (FC - 1);
    if (g >= NN) return;
    int s0 = off[g], s1 = off[g + 1];
    float acc = 0.0f;
    for (int i = s0; i < s1; ++i) {
        int r = src[i];
        acc += h2[(size_t)r * FC + f] * wgt[i];
    }
    float d2 = dis[g] * dis[g];
    float v = acc + h2[(size_t)g * FC + f] * d2 + b2[f];
    // log-softmax over the 16-lane group
    float m = v;
#pragma unroll
    for (int o = 1; o < FC; o <<= 1) m = fmaxf(m, __shfl_xor(m, o, FC));
    float e = __expf(v - m);
    float s = e;
#pragma unroll
    for (int o = 1; o < FC; o <<= 1) s += __shfl_xor(s, o, FC);
    out[(size_t)g * FC + f] = v - m - logf(s);
}

extern "C" void kernel_launch(void* const* d_in, const int* in_sizes, int n_in,
                              void* d_out, int out_size, void* d_ws, size_t ws_size,
                              hipStream_t stream) {
    const float* x  = (const float*)d_in[0];
    const int*   ei = (const int*)d_in[1];
    const float* W1 = (const float*)d_in[2];
    const float* b1 = (const float*)d_in[3];
    const float* W2 = (const float*)d_in[4];
    const float* b2 = (const float*)d_in[5];
    float* out = (float*)d_out;

    const int* row = ei;
    const int* col = ei + NE;

    // workspace layout (element counts padded for 16B alignment of h1/hr)
    int*   cnt  = (int*)d_ws;                 // NN
    int*   cur  = cnt + NN;                   // NN
    int*   off  = cur + NN;                   // NN+1 (padded to NN+4)
    int*   part = off + NN + 4;               // NBLK (padded to 100)
    float* dis  = (float*)(part + 100);       // NN
    int*   src  = (int*)(dis + NN);           // NE
    float* wgt  = (float*)(src + NE);         // NE
    float* h1   = wgt + NE;                   // NN*FH (16B-aligned)
    float* hr   = h1 + (size_t)NN * FH;       // NN*FH
    float* h2   = h1;                         // reuse: h1 dead after k_gather1

    hipMemsetAsync(cnt, 0, (size_t)NN * sizeof(int), stream);
    hipMemsetAsync(cur, 0, (size_t)NN * sizeof(int), stream);

    const int B = 256;
    int gbN = (NN + B - 1) / B;
    int gbE = (NE + B - 1) / B;

    k_count<<<gbE, B, 0, stream>>>(col, cnt);
    k_dis<<<gbN, B, 0, stream>>>(cnt, dis);
    k_blocksum<<<NBLK, SCAN_B, 0, stream>>>(cnt, part);
    k_scanpart<<<1, 64, 0, stream>>>(part);
    k_scanblock<<<NBLK, SCAN_B, 0, stream>>>(cnt, part, off);
    k_fill<<<gbE, B, 0, stream>>>(row, col, dis, off, cur, src, wgt);

    k_gemm1<<<gbN, B, 0, stream>>>(x, W1, h1);

    k_gather1<<<(NN * FH + B - 1) / B, B, 0, stream>>>(off, src, wgt, h1, dis, b1, hr);
    k_gemm2<<<gbN, B, 0, stream>>>(hr, W2, h2);
    k_gather2<<<(NN * FC + B - 1) / B, B, 0, stream>>>(off, src, wgt, h2, dis, b2, out);
}

// Round 3
// 412.428 us; speedup vs baseline: 1.1555x; 1.0090x over previous
//
#include <hip/hip_runtime.h>
#include <hip/hip_bf16.h>

#define NN 100000
#define NE 1600000
#define FIN 512
#define FH 32
#define FC 16
#define SCAN_B 1024
#define NBLK ((NN + SCAN_B - 1) / SCAN_B)  // 98
#define KHALF 256                          // split-K half size
#define GB1 ((NN + 255) / 256)             // 391 node-blocks

// ---------------- degree histogram ----------------

__global__ void k_count(const int* __restrict__ col, int* __restrict__ cnt) {
    int e = blockIdx.x * blockDim.x + threadIdx.x;
    if (e < NE) atomicAdd(&cnt[col[e]], 1);
}

__global__ void k_dis(const int* __restrict__ cnt, float* __restrict__ dis) {
    int n = blockIdx.x * blockDim.x + threadIdx.x;
    if (n < NN) dis[n] = rsqrtf((float)cnt[n] + 1.0f);  // +1 self-loop
}

// ---------------- exclusive prefix scan of cnt -> off ----------------

__global__ __launch_bounds__(SCAN_B) void k_blocksum(const int* __restrict__ cnt,
                                                     int* __restrict__ part) {
    __shared__ int s[SCAN_B];
    int i = blockIdx.x * SCAN_B + threadIdx.x;
    s[threadIdx.x] = (i < NN) ? cnt[i] : 0;
    __syncthreads();
    for (int st = SCAN_B / 2; st > 0; st >>= 1) {
        if (threadIdx.x < st) s[threadIdx.x] += s[threadIdx.x + st];
        __syncthreads();
    }
    if (threadIdx.x == 0) part[blockIdx.x] = s[0];
}

__global__ void k_scanpart(int* __restrict__ part) {
    if (threadIdx.x == 0 && blockIdx.x == 0) {
        int run = 0;
        for (int b = 0; b < NBLK; ++b) {
            int v = part[b];
            part[b] = run;
            run += v;
        }
    }
}

__global__ __launch_bounds__(SCAN_B) void k_scanblock(const int* __restrict__ cnt,
                                                      const int* __restrict__ part,
                                                      int* __restrict__ off) {
    __shared__ int s[SCAN_B];
    int i = blockIdx.x * SCAN_B + threadIdx.x;
    int v = (i < NN) ? cnt[i] : 0;
    s[threadIdx.x] = v;
    __syncthreads();
    for (int st = 1; st < SCAN_B; st <<= 1) {
        int add = (threadIdx.x >= st) ? s[threadIdx.x - st] : 0;
        __syncthreads();
        s[threadIdx.x] += add;
        __syncthreads();
    }
    if (i < NN) off[i] = part[blockIdx.x] + s[threadIdx.x] - v;  // exclusive
    if (i == NN - 1) off[NN] = part[blockIdx.x] + s[threadIdx.x];
}

// ---------------- CSR fill ----------------

__global__ void k_fill(const int* __restrict__ row, const int* __restrict__ col,
                       const float* __restrict__ dis, const int* __restrict__ off,
                       int* __restrict__ cur, int* __restrict__ src,
                       float* __restrict__ wgt) {
    int e = blockIdx.x * blockDim.x + threadIdx.x;
    if (e >= NE) return;
    int r = row[e], c = col[e];
    int p = off[c] + atomicAdd(&cur[c], 1);
    src[p] = r;
    wgt[p] = dis[r] * dis[c];
}

// ---------------- GEMM1 split-K: part[n] = x[n, ks:ks+256] @ W1[ks:ks+256] ----------------
// grid = 2*GB1; even blocks do K-half 0 -> p0, odd blocks K-half 1 -> p1.
// 8-deep float4 load batching for memory ILP.

__global__ __launch_bounds__(256) void k_gemm1s(const float* __restrict__ x,
                                                const float* __restrict__ W1,
                                                float* __restrict__ p0,
                                                float* __restrict__ p1) {
    int half = blockIdx.x & 1;
    int nb = blockIdx.x >> 1;
    int ks = half ? KHALF : 0;
    float* dst = half ? p1 : p0;

    __shared__ float Wl[KHALF * FH];  // 32 KB
    const float4* wsrc = (const float4*)(W1 + (size_t)ks * FH);
    for (int i = threadIdx.x; i < KHALF * FH / 4; i += 256)
        ((float4*)Wl)[i] = wsrc[i];
    __syncthreads();

    int n = nb * 256 + threadIdx.x;
    if (n >= NN) return;

    float acc[FH];
#pragma unroll
    for (int j = 0; j < FH; ++j) acc[j] = 0.0f;

    const float4* xr = (const float4*)(x + (size_t)n * FIN + ks);
    for (int kg = 0; kg < KHALF / 4; kg += 8) {
        float4 xv[8];
#pragma unroll
        for (int u = 0; u < 8; ++u) xv[u] = xr[kg + u];
#pragma unroll
        for (int u = 0; u < 8; ++u) {
            const float* xs = (const float*)&xv[u];
#pragma unroll
            for (int kk = 0; kk < 4; ++kk) {
                float xk = xs[kk];
                const float* wrow = &Wl[((kg + u) * 4 + kk) * FH];
#pragma unroll
                for (int j = 0; j < FH; ++j) acc[j] += xk * wrow[j];
            }
        }
    }
    float4* outp = (float4*)(dst + (size_t)n * FH);
#pragma unroll
    for (int j = 0; j < FH / 4; ++j)
        outp[j] = make_float4(acc[4 * j], acc[4 * j + 1], acc[4 * j + 2], acc[4 * j + 3]);
}

// ---------------- combine split-K partials: h1 += p1 (in place, h1 aliases p0) ----------------

__global__ void k_comb(float* __restrict__ h1, const float* __restrict__ p1) {
    int i = blockIdx.x * blockDim.x + threadIdx.x;
    if (i < NN * FH / 4) {
        float4 a = ((const float4*)h1)[i];
        float4 b = ((const float4*)p1)[i];
        ((float4*)h1)[i] = make_float4(a.x + b.x, a.y + b.y, a.z + b.z, a.w + b.w);
    }
}

// ---------------- gather layer1 + self-loop + bias + relu -> hr ----------------

__global__ __launch_bounds__(256) void k_gather1(const int* __restrict__ off,
                                                 const int* __restrict__ src,
                                                 const float* __restrict__ wgt,
                                                 const float* __restrict__ h1,
                                                 const float* __restrict__ dis,
                                                 const float* __restrict__ b1,
                                                 float* __restrict__ hr) {
    int g = blockIdx.x * (256 / FH) + threadIdx.x / FH;
    int f = threadIdx.x & (FH - 1);
    if (g >= NN) return;
    int s0 = off[g], s1 = off[g + 1];
    float acc = 0.0f;
    for (int i = s0; i < s1; ++i) {
        int r = src[i];
        acc += h1[(size_t)r * FH + f] * wgt[i];
    }
    float d2 = dis[g] * dis[g];
    float v = acc + h1[(size_t)g * FH + f] * d2 + b1[f];
    hr[(size_t)g * FH + f] = v > 0.0f ? v : 0.0f;
}

// ---------------- GEMM2: h2 = hr @ W2 (32 -> 16) ----------------

__global__ __launch_bounds__(256) void k_gemm2(const float* __restrict__ hr,
                                               const float* __restrict__ W2,
                                               float* __restrict__ h2) {
    __shared__ float Wl[FH * FC];  // 2 KB
    for (int i = threadIdx.x; i < FH * FC; i += 256) Wl[i] = W2[i];
    __syncthreads();
    int n = blockIdx.x * blockDim.x + threadIdx.x;
    if (n >= NN) return;
    float h[FH];
    const float4* hp = (const float4*)(hr + (size_t)n * FH);
#pragma unroll
    for (int j = 0; j < FH / 4; ++j) {
        float4 t = hp[j];
        h[4 * j] = t.x; h[4 * j + 1] = t.y; h[4 * j + 2] = t.z; h[4 * j + 3] = t.w;
    }
#pragma unroll
    for (int j = 0; j < FC; ++j) {
        float s = 0.0f;
#pragma unroll
        for (int k = 0; k < FH; ++k) s += h[k] * Wl[k * FC + j];
        h2[(size_t)n * FC + j] = s;
    }
}

// ---------------- gather layer2 + self-loop + bias + log_softmax -> out ----------------

__global__ __launch_bounds__(256) void k_gather2(const int* __restrict__ off,
                                                 const int* __restrict__ src,
                                                 const float* __restrict__ wgt,
                                                 const float* __restrict__ h2,
                                                 const float* __restrict__ dis,
                                                 const float* __restrict__ b2,
                                                 float* __restrict__ out) {
    int g = blockIdx.x * (256 / FC) + threadIdx.x / FC;
    int f = threadIdx.x & (FC - 1);
    if (g >= NN) return;
    int s0 = off[g], s1 = off[g + 1];
    float acc = 0.0f;
    for (int i = s0; i < s1; ++i) {
        int r = src[i];
        acc += h2[(size_t)r * FC + f] * wgt[i];
    }
    float d2 = dis[g] * dis[g];
    float v = acc + h2[(size_t)g * FC + f] * d2 + b2[f];
    float m = v;
#pragma unroll
    for (int o = 1; o < FC; o <<= 1) m = fmaxf(m, __shfl_xor(m, o, FC));
    float e = __expf(v - m);
    float s = e;
#pragma unroll
    for (int o = 1; o < FC; o <<= 1) s += __shfl_xor(s, o, FC);
    out[(size_t)g * FC + f] = v - m - logf(s);
}

extern "C" void kernel_launch(void* const* d_in, const int* in_sizes, int n_in,
                              void* d_out, int out_size, void* d_ws, size_t ws_size,
                              hipStream_t stream) {
    const float* x  = (const float*)d_in[0];
    const int*   ei = (const int*)d_in[1];
    const float* W1 = (const float*)d_in[2];
    const float* b1 = (const float*)d_in[3];
    const float* W2 = (const float*)d_in[4];
    const float* b2 = (const float*)d_in[5];
    float* out = (float*)d_out;

    const int* row = ei;
    const int* col = ei + NE;

    // workspace layout
    int*   cnt  = (int*)d_ws;                 // NN
    int*   cur  = cnt + NN;                   // NN
    int*   off  = cur + NN;                   // NN+1 (padded to NN+4)
    int*   part = off + NN + 4;               // NBLK (padded to 100)
    float* dis  = (float*)(part + 100);       // NN
    int*   src  = (int*)(dis + NN);           // NE
    float* wgt  = (float*)(src + NE);         // NE
    float* h1   = wgt + NE;                   // NN*FH  (= split-K partial p0)
    float* hr   = h1 + (size_t)NN * FH;       // NN*FH  (= split-K partial p1, then relu output)
    float* h2   = h1;                         // reuse: h1 dead after k_gather1

    hipMemsetAsync(cnt, 0, (size_t)NN * sizeof(int), stream);
    hipMemsetAsync(cur, 0, (size_t)NN * sizeof(int), stream);

    const int B = 256;
    int gbN = (NN + B - 1) / B;
    int gbE = (NE + B - 1) / B;

    k_count<<<gbE, B, 0, stream>>>(col, cnt);
    k_dis<<<gbN, B, 0, stream>>>(cnt, dis);
    k_blocksum<<<NBLK, SCAN_B, 0, stream>>>(cnt, part);
    k_scanpart<<<1, 64, 0, stream>>>(part);
    k_scanblock<<<NBLK, SCAN_B, 0, stream>>>(cnt, part, off);
    k_fill<<<gbE, B, 0, stream>>>(row, col, dis, off, cur, src, wgt);

    k_gemm1s<<<2 * GB1, B, 0, stream>>>(x, W1, h1, hr);
    k_comb<<<(NN * FH / 4 + B - 1) / B, B, 0, stream>>>(h1, hr);

    k_gather1<<<(NN * FH + B - 1) / B, B, 0, stream>>>(off, src, wgt, h1, dis, b1, hr);
    k_gemm2<<<gbN, B, 0, stream>>>(hr, W2, h2);
    k_gather2<<<(NN * FC + B - 1) / B, B, 0, stream>>>(off, src, wgt, h2, dis, b2, out);
}